// Round 1
// baseline (947.281 us; speedup 1.0000x reference)
//
#include <hip/hip_runtime.h>

// SoftmaxPooling on MI355X (gfx950) — round 2: occupancy unlock.
//   scores = tanh(h @ W1 + b1) @ w2 (+b2, cancels in softmax)
//   per-track (10 consecutive hits) softmax -> weights
//   pooled[track] = sum_i w_i * h[i]
//
// Change vs previous round: the 134 KiB per-block LDS stage of W1^T capped
// residency at 1 block/CU (OccupancyPercent 22.8, everything latency-bound).
// W1 is shared by all blocks and only 128 KiB as bf16, so:
//   - convert_w1_kernel writes W1^T bf16 into the workspace ONCE (L2-resident)
//   - main kernel reads B-fragments directly from global (L1/L2 hits)
//   - LDS drops 137216 B -> 640 B; occupancy becomes VGPR-bound
//   - NS=2 row-strips/wave keeps VGPRs ~110 (<=128 tier: 4 waves/SIMD,
//     16 waves/CU, 3 blocks/CU co-resident -> cross-block load/compute overlap)
// Block = 320 threads (5 waves), 16 tracks = 160 rows = 10 strips (2/wave).
// Grid = 50000/16 = 3125 blocks exactly, no remainder.

typedef __attribute__((ext_vector_type(8))) short short8;  // 8 bf16 (4 VGPRs) MFMA A/B frag
typedef __attribute__((ext_vector_type(4))) float f32x4;   // MFMA C/D frag

#define LATENT       256
#define HPT          10                  // hits per track
#define TPB_TRACKS   16                  // tracks per block
#define ROWS_PB      (TPB_TRACKS * HPT)  // 160 hit-rows per block
#define STRIPS_PB    (ROWS_PB / 16)      // 10 MFMA row-strips per block
#define WAVES        5
#define THREADS      (WAVES * 64)        // 320
#define NS           (STRIPS_PB / WAVES) // 2 strips per wave, uniform
#define LOG2E        1.44269504088896f

__device__ __forceinline__ short bf16_rne(float x) {
    // round-to-nearest-even fp32 -> bf16
    unsigned u = __float_as_uint(x);
    u += 0x7FFFu + ((u >> 16) & 1u);
    return (short)(u >> 16);
}

__device__ __forceinline__ float tanh_fast(float x) {
    // tanh(x) = 1 - 2/(e^{2x}+1); exp2-based, saturates correctly for |x| large
    float e = __builtin_amdgcn_exp2f(x * (2.0f * LOG2E));
    return 1.0f - 2.0f * __builtin_amdgcn_rcpf(e + 1.0f);
}

// ---------------- Pre-kernel: W1 fp32 [k][n] -> W1^T bf16 [n][k] in workspace ----------------
// 32768 threads, each packs 2 consecutive k for one n (coalesced reads over n).
__global__ __launch_bounds__(256)
void convert_w1_kernel(const float* __restrict__ W1, short* __restrict__ w1t) {
    int idx = blockIdx.x * 256 + threadIdx.x;   // 0 .. 256*128-1
    int n = idx & 255;
    int k = (idx >> 8) << 1;
    short2 p;
    p.x = bf16_rne(W1[(size_t)k * LATENT + n]);
    p.y = bf16_rne(W1[(size_t)(k + 1) * LATENT + n]);
    *(short2*)&w1t[n * LATENT + k] = p;
}

__global__ __launch_bounds__(THREADS, 4)   // force <=128 VGPR: 4 waves/SIMD tier
void softmax_pool_kernel(const float* __restrict__ h,
                         const short* __restrict__ w1t,   // bf16 W1^T [n][k], L2-resident
                         const float* __restrict__ b1,
                         const float* __restrict__ w2,
                         float* __restrict__ out,
                         int n_hits, int num_tracks)
{
    __shared__ float sc_lds[ROWS_PB];        // scores then softmax weights, 640 B total LDS

    const int tid  = threadIdx.x;
    const int wave = tid >> 6;
    const int lane = tid & 63;
    const int q    = lane >> 4;   // quad 0..3
    const int c    = lane & 15;   // low-4 lane id
    const int blk  = blockIdx.x;

    // ---------------- Phase B: scores via MFMA ----------------
    // Wave w owns strips {w, w+5}. A fragments held in registers (64 VGPRs):
    // a[st][kt] = h[row = strip*16 + c][k = kt*32 + q*8 + 0..7] as bf16.
    short8 a[NS][8];
    #pragma unroll
    for (int st = 0; st < NS; ++st) {
        int strip = wave + st * WAVES;
        long row = (long)blk * ROWS_PB + strip * 16 + c;
        if (row >= n_hits) row = n_hits - 1;   // safe clamp (grid divides exactly anyway)
        const float* hrow = h + (size_t)row * LATENT + q * 8;
        #pragma unroll
        for (int kt = 0; kt < 8; ++kt) {
            float4 f0 = *(const float4*)(hrow + kt * 32);
            float4 f1 = *(const float4*)(hrow + kt * 32 + 4);
            short8 v;
            v[0] = bf16_rne(f0.x); v[1] = bf16_rne(f0.y);
            v[2] = bf16_rne(f0.z); v[3] = bf16_rne(f0.w);
            v[4] = bf16_rne(f1.x); v[5] = bf16_rne(f1.y);
            v[6] = bf16_rne(f1.z); v[7] = bf16_rne(f1.w);
            a[st][kt] = v;
        }
    }

    f32x4 zero4 = {0.0f, 0.0f, 0.0f, 0.0f};
    f32x4 sc[NS] = {zero4, zero4};           // per-strip per-row score partials

    #pragma unroll 1                          // keep register pressure flat across ct
    for (int ct = 0; ct < 16; ++ct) {         // 16 column-tiles of 16
        int n = ct * 16 + c;
        float b1n = b1[n];
        float w2n = w2[n];
        // B-fragment straight from global: row n of W1^T, 16 B/lane, 64 B/row
        // segments -> 16 cache lines per wave-load, all L1/L2 hits after warmup.
        const short* bbase = w1t + n * LATENT + q * 8;
        f32x4 acc[NS] = {zero4, zero4};
        #pragma unroll
        for (int kt = 0; kt < 8; ++kt) {
            short8 bf = *(const short8*)(bbase + kt * 32);
            #pragma unroll
            for (int st = 0; st < NS; ++st)
                acc[st] = __builtin_amdgcn_mfma_f32_16x16x32_bf16(a[st][kt], bf, acc[st], 0, 0, 0);
        }
        // acc[st][r] = u[row = strip*16 + q*4 + r][n];  fold tanh + dot(w2)
        #pragma unroll
        for (int st = 0; st < NS; ++st) {
            #pragma unroll
            for (int r = 0; r < 4; ++r)
                sc[st][r] += w2n * tanh_fast(acc[st][r] + b1n);
        }
    }

    // Reduce score partials across the 16 column-lanes (same quad)
    #pragma unroll
    for (int st = 0; st < NS; ++st) {
        #pragma unroll
        for (int r = 0; r < 4; ++r) {
            float v = sc[st][r];
            v += __shfl_xor(v, 1);
            v += __shfl_xor(v, 2);
            v += __shfl_xor(v, 4);
            v += __shfl_xor(v, 8);
            sc[st][r] = v;
        }
    }
    if (c == 0) {
        #pragma unroll
        for (int st = 0; st < NS; ++st) {
            int strip = wave + st * WAVES;
            float4 o;
            o.x = sc[st][0]; o.y = sc[st][1]; o.z = sc[st][2]; o.w = sc[st][3];
            *(float4*)&sc_lds[strip * 16 + q * 4] = o;   // rows strip*16 + q*4 .. +3
        }
    }
    __syncthreads();

    // ---------------- Phase C: per-track softmax (scores -> weights, in place) ----------------
    if (tid < TPB_TRACKS) {
        int tg = blk * TPB_TRACKS + tid;
        if (tg < num_tracks) {
            float s[HPT];
            float m = -1e30f;
            #pragma unroll
            for (int i = 0; i < HPT; ++i) {
                s[i] = sc_lds[tid * HPT + i];
                m = fmaxf(m, s[i]);
            }
            float sum = 0.0f;
            #pragma unroll
            for (int i = 0; i < HPT; ++i) {
                s[i] = __builtin_amdgcn_exp2f((s[i] - m) * LOG2E);
                sum += s[i];
            }
            float inv = __builtin_amdgcn_rcpf(sum);
            #pragma unroll
            for (int i = 0; i < HPT; ++i)
                sc_lds[tid * HPT + i] = s[i] * inv;
        }
    }
    __syncthreads();

    // ---------------- Phase D: weighted pooling ----------------
    // h rows re-read from global; per-block span (160 KB) is L3-resident from
    // Phase B (validated: FETCH_SIZE ~= one pass over h). Lane owns 4 cols.
    for (int t = wave; t < TPB_TRACKS; t += WAVES) {
        int tg = blk * TPB_TRACKS + t;
        if (tg >= num_tracks) continue;
        const float* hb = h + (size_t)tg * HPT * LATENT + lane * 4;
        float4 acc = {0.0f, 0.0f, 0.0f, 0.0f};
        #pragma unroll
        for (int i = 0; i < HPT; ++i) {
            float wi = sc_lds[t * HPT + i];
            float4 v = *(const float4*)(hb + (size_t)i * LATENT);
            acc.x += wi * v.x;
            acc.y += wi * v.y;
            acc.z += wi * v.z;
            acc.w += wi * v.w;
        }
        *(float4*)(out + (size_t)tg * LATENT + lane * 4) = acc;
    }
}

extern "C" void kernel_launch(void* const* d_in, const int* in_sizes, int n_in,
                              void* d_out, int out_size, void* d_ws, size_t ws_size,
                              hipStream_t stream) {
    const float* h  = (const float*)d_in[0];
    const float* W1 = (const float*)d_in[1];
    const float* b1 = (const float*)d_in[2];
    const float* w2 = (const float*)d_in[3];
    // d_in[4] = b2 (cancels in softmax), d_in[5] = batch_indices (structure i/10 guaranteed),
    // d_in[6] = num_tracks (derived from out_size instead; device scalar unreadable on host)
    float* out = (float*)d_out;
    short* w1t = (short*)d_ws;               // 131072 B of workspace for bf16 W1^T

    int n_hits     = in_sizes[0] / LATENT;    // 500000
    int num_tracks = out_size / LATENT;       // 50000
    int blocks     = (num_tracks + TPB_TRACKS - 1) / TPB_TRACKS;   // 3125 exactly

    convert_w1_kernel<<<128, 256, 0, stream>>>(W1, w1t);
    softmax_pool_kernel<<<blocks, THREADS, 0, stream>>>(h, w1t, b1, w2, out,
                                                        n_hits, num_tracks);
}

// Round 2
// 891.119 us; speedup vs baseline: 1.0630x; 1.0630x over previous
//
#include <hip/hip_runtime.h>

// SoftmaxPooling on MI355X (gfx950) — round 3: 2 blocks/CU via split-N W1 staging.
//   scores = tanh(h @ W1 + b1) @ w2 (+b2, cancels in softmax)
//   per-track (10 consecutive hits) softmax -> weights
//   pooled[track] = sum_i w_i * h[i]
//
// History:
//   round 0 (340us/disp): full 135KiB LDS W1^T -> 1 block/CU, phases serialize, 24% occ.
//   round 1 (445us/disp): all-global B + __launch_bounds__(320,4) -> allocator over-restricted
//                         (5-wave block!), spilled ~29 dwords/thread (WRITE 88->167MB), MfmaUtil 5.8.
// This round:
//   - convert W1 -> bf16 W1^T linear workspace once (L2-resident, 128 KiB)
//   - stage LOWER half n in [0,128) into 64 KiB LDS, XOR-swizzled (byte ^= (n&7)<<4):
//     conflict-free-ish ds_read_b128 (residual 2-way = free), linear global reads
//   - UPPER half n in [128,256): B-frags straight from L2 (halves round-1 L2 traffic)
//   - 8-wave 512-thread blocks, 24 tracks (15 strips, NS<=2): ~115 VGPR, fits 128 tier
//     under __launch_bounds__(512,4) = exactly 2 blocks/CU -> cross-block mem/compute overlap
//   - global-B half runs BEFORE the staging barrier (no LDS dependency) to hide it

typedef __attribute__((ext_vector_type(8))) short short8;  // 8 bf16 (4 VGPRs) MFMA A/B frag
typedef __attribute__((ext_vector_type(4))) float f32x4;   // MFMA C/D frag

#define LATENT       256
#define HPT          10                  // hits per track
#define TPB_TRACKS   24                  // tracks per block
#define ROWS_PB      (TPB_TRACKS * HPT)  // 240 hit-rows per block
#define STRIPS_PB    (ROWS_PB / 16)      // 15 MFMA row-strips per block
#define WAVES        8
#define THREADS      (WAVES * 64)        // 512
#define LOG2E        1.44269504088896f

__device__ __forceinline__ short bf16_rne(float x) {
    // round-to-nearest-even fp32 -> bf16
    unsigned u = __float_as_uint(x);
    u += 0x7FFFu + ((u >> 16) & 1u);
    return (short)(u >> 16);
}

__device__ __forceinline__ float tanh_fast(float x) {
    // tanh(x) = 1 - 2/(e^{2x}+1); exp2-based, saturates correctly for |x| large
    float e = __builtin_amdgcn_exp2f(x * (2.0f * LOG2E));
    return 1.0f - 2.0f * __builtin_amdgcn_rcpf(e + 1.0f);
}

// ---------------- Pre-kernel: W1 fp32 [k][n] -> W1^T bf16 [n][k] linear in workspace ----------------
__global__ __launch_bounds__(256)
void convert_w1_kernel(const float* __restrict__ W1, short* __restrict__ w1t) {
    int idx = blockIdx.x * 256 + threadIdx.x;   // 0 .. 256*128-1
    int n = idx & 255;
    int k = (idx >> 8) << 1;
    short2 p;
    p.x = bf16_rne(W1[(size_t)k * LATENT + n]);
    p.y = bf16_rne(W1[(size_t)(k + 1) * LATENT + n]);
    *(short2*)&w1t[n * LATENT + k] = p;
}

__global__ __launch_bounds__(THREADS, 4)   // 4 waves/EU = 2x 8-wave blocks/CU; VGPR<=128
void softmax_pool_kernel(const float* __restrict__ h,
                         const short* __restrict__ w1t,   // bf16 W1^T [n][k] linear, L2-resident
                         const float* __restrict__ b1,
                         const float* __restrict__ w2,
                         float* __restrict__ out,
                         int n_hits, int num_tracks)
{
    __shared__ short w1_lds[128 * 256];      // lower-half W1^T bf16, XOR-swizzled, 65536 B
    __shared__ float sc_lds[ROWS_PB];        // scores then softmax weights, 960 B

    const int tid  = threadIdx.x;
    const int wave = tid >> 6;
    const int lane = tid & 63;
    const int q    = lane >> 4;   // quad 0..3
    const int c    = lane & 15;   // low-4 lane id
    const int blk  = blockIdx.x;

    // ---------------- Phase A1: stage lower W1^T half (n<128) into LDS, swizzled ----------------
    // 64 KiB = 4096 x 16B chunks; 8 iterations of 512 threads. Global reads linear/coalesced;
    // LDS writes at byte ^ ((n&7)<<4)  (n = row = chunk>>5): spreads 8 consecutive rows
    // across 8 distinct 16B bank slots -> residual 2-way conflict only (free).
    {
        const char* src = (const char*)w1t;
        char* dst = (char*)w1_lds;
        #pragma unroll
        for (int it = 0; it < 8; ++it) {
            int chunk = it * THREADS + tid;
            int lin = chunk << 4;
            int sw  = lin ^ (((chunk >> 5) & 7) << 4);
            *(short8*)(dst + sw) = *(const short8*)(src + lin);
        }
    }

    // ---------------- Phase A2: load + convert A fragments (h rows, bf16) ----------------
    // Wave w owns strips {w, w+8 (if <15)}. a[st][kt] = h[strip*16 + c][kt*32 + q*8 .. +7].
    const int ns = (wave < STRIPS_PB - WAVES) ? 2 : 1;   // waves 0..6: 2 strips, wave 7: 1

    short8 a[2][8];
    #pragma unroll
    for (int st = 0; st < 2; ++st) {
        if (st < ns) {
            int strip = wave + st * WAVES;
            long row = (long)blk * ROWS_PB + strip * 16 + c;
            if (row >= n_hits) row = n_hits - 1;   // tail-block clamp
            const float* hrow = h + (size_t)row * LATENT + q * 8;
            #pragma unroll
            for (int kt = 0; kt < 8; ++kt) {
                float4 f0 = *(const float4*)(hrow + kt * 32);
                float4 f1 = *(const float4*)(hrow + kt * 32 + 4);
                short8 v;
                v[0] = bf16_rne(f0.x); v[1] = bf16_rne(f0.y);
                v[2] = bf16_rne(f0.z); v[3] = bf16_rne(f0.w);
                v[4] = bf16_rne(f1.x); v[5] = bf16_rne(f1.y);
                v[6] = bf16_rne(f1.z); v[7] = bf16_rne(f1.w);
                a[st][kt] = v;
            }
        }
    }

    f32x4 zero4 = {0.0f, 0.0f, 0.0f, 0.0f};
    f32x4 sc[2] = {zero4, zero4};            // per-strip per-row score partials

    // ---------------- Phase B-upper: ct 8..15, B-frags from global (L2) ----------------
    // No dependency on the LDS stage -> runs before the barrier, hiding it.
    #pragma unroll 1
    for (int ct = 8; ct < 16; ++ct) {
        int n = ct * 16 + c;
        float b1n = b1[n];
        float w2n = w2[n];
        const short* bbase = w1t + n * LATENT + q * 8;
        f32x4 acc[2] = {zero4, zero4};
        #pragma unroll
        for (int kt = 0; kt < 8; ++kt) {
            short8 bf = *(const short8*)(bbase + kt * 32);
            #pragma unroll
            for (int st = 0; st < 2; ++st)
                if (st < ns)
                    acc[st] = __builtin_amdgcn_mfma_f32_16x16x32_bf16(a[st][kt], bf, acc[st], 0, 0, 0);
        }
        #pragma unroll
        for (int st = 0; st < 2; ++st)
            if (st < ns)
                #pragma unroll
                for (int r = 0; r < 4; ++r)
                    sc[st][r] += w2n * tanh_fast(acc[st][r] + b1n);
    }

    __syncthreads();   // staging writes visible; only barrier before softmax phases

    // ---------------- Phase B-lower: ct 0..7, B-frags from LDS (swizzled) ----------------
    #pragma unroll 1
    for (int ct = 0; ct < 8; ++ct) {
        int n = ct * 16 + c;
        float b1n = b1[n];
        float w2n = w2[n];
        const char* lbase = (const char*)w1_lds;
        int rowoff = n * 512;
        int swz = ((n & 7) << 4);
        f32x4 acc[2] = {zero4, zero4};
        #pragma unroll
        for (int kt = 0; kt < 8; ++kt) {
            int off = (rowoff + kt * 64 + q * 16) ^ swz;
            short8 bf = *(const short8*)(lbase + off);
            #pragma unroll
            for (int st = 0; st < 2; ++st)
                if (st < ns)
                    acc[st] = __builtin_amdgcn_mfma_f32_16x16x32_bf16(a[st][kt], bf, acc[st], 0, 0, 0);
        }
        #pragma unroll
        for (int st = 0; st < 2; ++st)
            if (st < ns)
                #pragma unroll
                for (int r = 0; r < 4; ++r)
                    sc[st][r] += w2n * tanh_fast(acc[st][r] + b1n);
    }

    // ---------------- Reduce score partials across the 16 column-lanes (same quad) ----------------
    #pragma unroll
    for (int st = 0; st < 2; ++st) {
        #pragma unroll
        for (int r = 0; r < 4; ++r) {
            float v = sc[st][r];
            v += __shfl_xor(v, 1);
            v += __shfl_xor(v, 2);
            v += __shfl_xor(v, 4);
            v += __shfl_xor(v, 8);
            sc[st][r] = v;
        }
    }
    if (c == 0) {
        #pragma unroll
        for (int st = 0; st < 2; ++st) {
            if (st < ns) {
                int strip = wave + st * WAVES;
                float4 o;
                o.x = sc[st][0]; o.y = sc[st][1]; o.z = sc[st][2]; o.w = sc[st][3];
                *(float4*)&sc_lds[strip * 16 + q * 4] = o;   // rows strip*16 + q*4 .. +3
            }
        }
    }
    __syncthreads();

    // ---------------- Phase C: per-track softmax (scores -> weights, in place) ----------------
    if (tid < TPB_TRACKS) {
        int tg = blk * TPB_TRACKS + tid;
        if (tg < num_tracks) {
            float s[HPT];
            float m = -1e30f;
            #pragma unroll
            for (int i = 0; i < HPT; ++i) {
                s[i] = sc_lds[tid * HPT + i];
                m = fmaxf(m, s[i]);
            }
            float sum = 0.0f;
            #pragma unroll
            for (int i = 0; i < HPT; ++i) {
                s[i] = __builtin_amdgcn_exp2f((s[i] - m) * LOG2E);
                sum += s[i];
            }
            float inv = __builtin_amdgcn_rcpf(sum);
            #pragma unroll
            for (int i = 0; i < HPT; ++i)
                sc_lds[tid * HPT + i] = s[i] * inv;
        }
    }
    __syncthreads();

    // ---------------- Phase D: weighted pooling ----------------
    // 3 contiguous tracks per wave; h slice still L2/L3-warm from Phase A2. Lane owns 4 cols.
    #pragma unroll
    for (int i = 0; i < 3; ++i) {
        int t = wave * 3 + i;
        int tg = blk * TPB_TRACKS + t;
        if (tg >= num_tracks) continue;
        const float* hb = h + (size_t)tg * HPT * LATENT + lane * 4;
        float4 acc = {0.0f, 0.0f, 0.0f, 0.0f};
        #pragma unroll
        for (int j = 0; j < HPT; ++j) {
            float wi = sc_lds[t * HPT + j];
            float4 v = *(const float4*)(hb + (size_t)j * LATENT);
            acc.x += wi * v.x;
            acc.y += wi * v.y;
            acc.z += wi * v.z;
            acc.w += wi * v.w;
        }
        *(float4*)(out + (size_t)tg * LATENT + lane * 4) = acc;
    }
}

extern "C" void kernel_launch(void* const* d_in, const int* in_sizes, int n_in,
                              void* d_out, int out_size, void* d_ws, size_t ws_size,
                              hipStream_t stream) {
    const float* h  = (const float*)d_in[0];
    const float* W1 = (const float*)d_in[1];
    const float* b1 = (const float*)d_in[2];
    const float* w2 = (const float*)d_in[3];
    // d_in[4] = b2 (cancels in softmax), d_in[5] = batch_indices (structure i/10 guaranteed)
    float* out = (float*)d_out;
    short* w1t = (short*)d_ws;               // 131072 B workspace: bf16 W1^T linear

    int n_hits     = in_sizes[0] / LATENT;    // 500000
    int num_tracks = out_size / LATENT;       // 50000
    int blocks     = (num_tracks + TPB_TRACKS - 1) / TPB_TRACKS;   // 2084 (8-track tail)

    convert_w1_kernel<<<128, 256, 0, stream>>>(W1, w1t);
    softmax_pool_kernel<<<blocks, THREADS, 0, stream>>>(h, w1t, b1, w2, out,
                                                        n_hits, num_tracks);
}